// Round 5
// baseline (689.627 us; speedup 1.0000x reference)
//
#include <hip/hip_runtime.h>
#include <hip/hip_bf16.h>

#define DDIM 2048
#define TTIMES 256
#define BM 64
#define BK 256
#define NTB 8              // 2048/256 big-steps
#define THREADS 512

typedef __attribute__((ext_vector_type(8))) short short8;
typedef __attribute__((ext_vector_type(4))) float f32x4;

__device__ __forceinline__ ushort f2bf(float f) {
    union { float f; unsigned int u; } v; v.f = f;
    unsigned int u = v.u;
    unsigned int r = (u + 0x7FFFu + ((u >> 16) & 1u)) >> 16;   // RNE
    return (ushort)r;
}
__device__ __forceinline__ float bf2f(ushort u) {
    union { unsigned int u; float f; } v; v.u = ((unsigned int)u) << 16;
    return v.f;
}
__device__ __forceinline__ ushort cvt1(float f) {
    union { __hip_bfloat16 h; ushort u; } cv;
    cv.h = __float2bfloat16(f);          // hardware RNE cvt
    return cv.u;
}

// ---------------- normalize org rows -> bf16 o in workspace ----------------
__global__ void norm_rows(const float* __restrict__ org, ushort* __restrict__ obf) {
    const int a   = blockIdx.x;
    const int tid = threadIdx.x;    // 256 threads
    const float* row = org + (size_t)a * DDIM;
    float4 v0 = ((const float4*)row)[tid * 2];
    float4 v1 = ((const float4*)row)[tid * 2 + 1];
    float s = v0.x*v0.x + v0.y*v0.y + v0.z*v0.z + v0.w*v0.w
            + v1.x*v1.x + v1.y*v1.y + v1.z*v1.z + v1.w*v1.w;
    #pragma unroll
    for (int off = 1; off < 64; off <<= 1) s += __shfl_xor(s, off);
    __shared__ float wsum[4];
    const int lane = tid & 63, w = tid >> 6;
    if (lane == 0) wsum[w] = s;
    __syncthreads();
    const float tot = wsum[0] + wsum[1] + wsum[2] + wsum[3];
    const float scale = 1.0f / fmaxf(sqrtf(tot), 1e-12f);
    union { ushort u[8]; uint4 v; } pk;
    pk.u[0] = f2bf(v0.x * scale); pk.u[1] = f2bf(v0.y * scale);
    pk.u[2] = f2bf(v0.z * scale); pk.u[3] = f2bf(v0.w * scale);
    pk.u[4] = f2bf(v1.x * scale); pk.u[5] = f2bf(v1.y * scale);
    pk.u[6] = f2bf(v1.z * scale); pk.u[7] = f2bf(v1.w * scale);
    ((uint4*)(obf + (size_t)a * DDIM))[tid] = pk.v;
}

// ---- BK=256 page-local GEMM + fused trace ----
// Block: 512 thr = 8 waves (2 wm x 4 wn). Tile: 64 rows x 256 times x 256 K.
// A: fp32 global->reg (1 KB contiguous per row per big-step) -> cvt -> swizzled
//    ds_write; 2 x 32 KB LDS double buffer; 1 lgkm-barrier per big-step.
// B: global->reg direct (L1/L2-hot obf), parity double-buffered per sub-step.
__global__ __launch_bounds__(THREADS, 4) void gemm_trace(
    const float* __restrict__ x, const ushort* __restrict__ obf,
    float* __restrict__ part)
{
    __shared__ __align__(16) ushort Ab[2][BM * BK];   // 2 x 32 KB

    const int tid  = threadIdx.x;
    const int lane = tid & 63;
    const int wid  = tid >> 6;
    const int wm   = wid >> 2;        // 0..1 (row half of 32)
    const int wn   = wid & 3;         // 0..3 (time quarter)
    const int rb   = blockIdx.x;      // 0..31 (row block of 64)
    const int d    = blockIdx.y;      // 0..31 (batch)

    // ---- A staging: thread owns row r_st, bf16 slots {j_st + 8i} ----
    const int r_st = tid >> 3;        // 0..63
    const int j_st = tid & 7;         // 0..7
    const float* abase = x + (size_t)d * DDIM * DDIM
                           + (size_t)(rb * BM + r_st) * DDIM;
    int wslot[4];
    #pragma unroll
    for (int i = 0; i < 4; ++i)
        wslot[i] = r_st * BK + ((j_st + 8 * i) ^ (r_st & 7)) * 8;   // ushort units

    // ---- fragment indices ----
    const int lr = lane & 15, lq = lane >> 4;
    const int rx7 = lr & 7;           // (frag row) & 7
    const ushort* bbase = obf + (size_t)(wn * 64 + lr) * DDIM + lq * 8;
    const int aro0 = (wm * 32 + lr) * BK;
    const int aro1 = (wm * 32 + 16 + lr) * BK;

    f32x4 acc[2][4];
    #pragma unroll
    for (int mi = 0; mi < 2; ++mi)
        #pragma unroll
        for (int ni = 0; ni < 4; ++ni)
            acc[mi][ni] = (f32x4){0.f, 0.f, 0.f, 0.f};

    float4 stg[4][2];                 // A staging regs (compile-time indexed)
    short8 b0[4], b1[4];              // B parity buffers

#define LOAD_A(T) do {                                                      \
    _Pragma("unroll")                                                       \
    for (int i = 0; i < 4; ++i) {                                           \
        const float* p_ = abase + (size_t)(T) * BK + (j_st + 8 * i) * 8;    \
        stg[i][0] = *(const float4*)p_;                                     \
        stg[i][1] = *(const float4*)(p_ + 4);                               \
    }                                                                       \
} while (0)

#define WRITE_A(buf) do {                                                   \
    _Pragma("unroll")                                                       \
    for (int i = 0; i < 4; ++i) {                                           \
        union { ushort u[8]; uint4 v; } pk_;                                \
        pk_.u[0] = cvt1(stg[i][0].x); pk_.u[1] = cvt1(stg[i][0].y);         \
        pk_.u[2] = cvt1(stg[i][0].z); pk_.u[3] = cvt1(stg[i][0].w);         \
        pk_.u[4] = cvt1(stg[i][1].x); pk_.u[5] = cvt1(stg[i][1].y);         \
        pk_.u[6] = cvt1(stg[i][1].z); pk_.u[7] = cvt1(stg[i][1].w);         \
        *(uint4*)&Ab[buf][wslot[i]] = pk_.v;                                \
    }                                                                       \
} while (0)

#define LOAD_B(T, ss, arr) do {                                             \
    _Pragma("unroll")                                                       \
    for (int ni = 0; ni < 4; ++ni)                                          \
        arr[ni] = *(const short8*)(bbase + (size_t)ni * 16 * DDIM           \
                                   + (T) * BK + (ss) * 32);                 \
} while (0)

#define SUB(buf, ss, bc) do {                                               \
    const short8 af0 = *(const short8*)&Ab[buf][aro0 + ((((ss)*4)+lq)^rx7)*8]; \
    const short8 af1 = *(const short8*)&Ab[buf][aro1 + ((((ss)*4)+lq)^rx7)*8]; \
    _Pragma("unroll")                                                       \
    for (int ni = 0; ni < 4; ++ni) {                                        \
        acc[0][ni] = __builtin_amdgcn_mfma_f32_16x16x32_bf16(               \
            af0, bc[ni], acc[0][ni], 0, 0, 0);                              \
        acc[1][ni] = __builtin_amdgcn_mfma_f32_16x16x32_bf16(               \
            af1, bc[ni], acc[1][ni], 0, 0, 0);                              \
    }                                                                       \
} while (0)

#define BIGSTEP(cur, T, islast) do {                                        \
    LOAD_B(T, 1, b1); SUB(cur, 0, b0);                                      \
    LOAD_B(T, 2, b0); SUB(cur, 1, b1);                                      \
    LOAD_B(T, 3, b1); SUB(cur, 2, b0);                                      \
    LOAD_B(T, 4, b0); SUB(cur, 3, b1);                                      \
    LOAD_B(T, 5, b1); SUB(cur, 4, b0);                                      \
    LOAD_B(T, 6, b0); SUB(cur, 5, b1);                                      \
    LOAD_B(T, 7, b1); SUB(cur, 6, b0);                                      \
    if (!(islast)) LOAD_B((T) + 1, 0, b0);                                  \
    SUB(cur, 7, b1);                                                        \
} while (0)

#define BARX do {                                                           \
    __builtin_amdgcn_sched_barrier(0);                                      \
    asm volatile("s_waitcnt lgkmcnt(0)" ::: "memory");                      \
    __builtin_amdgcn_s_barrier();                                           \
    __builtin_amdgcn_sched_barrier(0); } while (0)

    // ---- prologue ----
    LOAD_A(0);
    WRITE_A(0);                       // compiler waits A(0) arrival
    LOAD_A(1);                        // in flight across barrier (no vmcnt drain)
    LOAD_B(0, 0, b0);
    BARX;

    #pragma unroll 1
    for (int T = 0; T < NTB; ++T) {
        const int cur = T & 1;
        if (T + 1 < NTB) {
            WRITE_A(cur ^ 1);         // A(T+1) regs -> LDS nxt
            if (T + 2 < NTB) LOAD_A(T + 2);
            __builtin_amdgcn_sched_barrier(0);   // pin loads/writes before compute
            BIGSTEP(cur, T, 0);
        } else {
            BIGSTEP(cur, T, 1);
        }
        BARX;
    }

#undef LOAD_A
#undef WRITE_A
#undef LOAD_B
#undef SUB
#undef BIGSTEP
#undef BARX

    // ---- fused trace epilogue ----
    // acc[mi][ni][j]: row = rb*64 + wm*32 + mi*16 + lq*4 + j,
    //                 time = wn*64 + ni*16 + lr
    float* plds = (float*)&Ab[0][0];

    #pragma unroll
    for (int ni = 0; ni < 4; ++ni) {
        const int a_idx = wn * 64 + ni * 16 + lr;
        float ps = 0.f;
        #pragma unroll
        for (int mi = 0; mi < 2; ++mi) {
            const int bg = rb * BM + wm * 32 + mi * 16 + lq * 4;
            const ushort4 w = *(const ushort4*)(obf + (size_t)a_idx * DDIM + bg);
            ps += bf2f(w.x) * acc[mi][ni][0];
            ps += bf2f(w.y) * acc[mi][ni][1];
            ps += bf2f(w.z) * acc[mi][ni][2];
            ps += bf2f(w.w) * acc[mi][ni][3];
        }
        ps += __shfl_xor(ps, 16);
        ps += __shfl_xor(ps, 32);
        if (lane < 16) plds[wm * 256 + a_idx] = ps;
    }
    __syncthreads();
    if (tid < 256)
        part[((size_t)d * 32 + rb) * TTIMES + tid] = plds[tid] + plds[256 + tid];
}

// ---------------- final reduce over row-blocks ----------------
__global__ void reduce_part(const float* __restrict__ part, float* __restrict__ out) {
    const int d = blockIdx.x;    // 32
    const int a = threadIdx.x;   // 256
    float s = 0.f;
    #pragma unroll
    for (int rb = 0; rb < 32; ++rb)
        s += part[((size_t)d * 32 + rb) * TTIMES + a];
    out[(size_t)d * TTIMES + a] = s;
}

extern "C" void kernel_launch(void* const* d_in, const int* in_sizes, int n_in,
                              void* d_out, int out_size, void* d_ws, size_t ws_size,
                              hipStream_t stream) {
    const float* x   = (const float*)d_in[0];   // (32, 2048, 2048) fp32
    const float* org = (const float*)d_in[1];   // (256, 2048) fp32
    float* out = (float*)d_out;                 // (32, 256) fp32

    ushort* obf = (ushort*)d_ws;                          // 1 MiB bf16 normalized o
    float*  prt = (float*)((char*)d_ws + (1 << 20));      // 1 MiB partials (32x32x256)

    norm_rows<<<dim3(TTIMES), dim3(256), 0, stream>>>(org, obf);
    gemm_trace<<<dim3(32, 32), dim3(THREADS), 0, stream>>>(x, obf, prt);
    reduce_part<<<dim3(32), dim3(256), 0, stream>>>(prt, out);
}

// Round 6
// 134.413 us; speedup vs baseline: 5.1307x; 5.1307x over previous
//
#include <hip/hip_runtime.h>
#include <hip/hip_bf16.h>

#define DDIM 2048
#define TTIMES 256
#define NT 64                 // K-steps of 32
#define THREADS 512

typedef __attribute__((ext_vector_type(8))) short short8;
typedef __attribute__((ext_vector_type(4))) float f32x4;

using gvoid = const __attribute__((address_space(1))) void;
using svoid = __attribute__((address_space(3))) void;

__device__ __forceinline__ void gld16(const void* g, void* l) {
    __builtin_amdgcn_global_load_lds((gvoid*)g, (svoid*)l, 16, 0, 0);
}

__device__ __forceinline__ ushort f2bf(float f) {
    union { float f; unsigned int u; } v; v.f = f;
    unsigned int u = v.u;
    unsigned int r = (u + 0x7FFFu + ((u >> 16) & 1u)) >> 16;   // RNE
    return (ushort)r;
}
__device__ __forceinline__ float bf2f(ushort u) {
    union { unsigned int u; float f; } v; v.u = ((unsigned int)u) << 16;
    return v.f;
}
__device__ __forceinline__ short cvt1(float f) {
    union { __hip_bfloat16 h; ushort u; } cv;
    cv.h = __float2bfloat16(f);          // hardware RNE cvt
    return (short)cv.u;
}

// ---------------- normalize org rows -> bf16 o in workspace ----------------
__global__ void norm_rows(const float* __restrict__ org, ushort* __restrict__ obf) {
    const int a   = blockIdx.x;     // time row
    const int tid = threadIdx.x;    // 256 threads
    const float* row = org + (size_t)a * DDIM;
    float4 v0 = ((const float4*)row)[tid * 2];
    float4 v1 = ((const float4*)row)[tid * 2 + 1];
    float s = v0.x*v0.x + v0.y*v0.y + v0.z*v0.z + v0.w*v0.w
            + v1.x*v1.x + v1.y*v1.y + v1.z*v1.z + v1.w*v1.w;
    #pragma unroll
    for (int off = 1; off < 64; off <<= 1) s += __shfl_xor(s, off);
    __shared__ float wsum[4];
    const int lane = tid & 63, w = tid >> 6;
    if (lane == 0) wsum[w] = s;
    __syncthreads();
    const float tot = wsum[0] + wsum[1] + wsum[2] + wsum[3];
    const float scale = 1.0f / fmaxf(sqrtf(tot), 1e-12f);
    union { ushort u[8]; uint4 v; } pk;
    pk.u[0] = f2bf(v0.x * scale); pk.u[1] = f2bf(v0.y * scale);
    pk.u[2] = f2bf(v0.z * scale); pk.u[3] = f2bf(v0.w * scale);
    pk.u[4] = f2bf(v1.x * scale); pk.u[5] = f2bf(v1.y * scale);
    pk.u[6] = f2bf(v1.z * scale); pk.u[7] = f2bf(v1.w * scale);
    ((uint4*)(obf + (size_t)a * DDIM))[tid] = pk.v;
}

// ---- gload_lds double-buffered GEMM + fused trace, K-phase-staggered ----
// Identical to round-3 structure EXCEPT: each block starts its K sweep at
// t0 = linear_block_id & 63, wrapping mod 64 — so at any instant the 512
// blocks collectively touch all 64 K-column phases (spreads HBM channel use;
// anti-partition-camping). fp32 accumulate order changes only.
__global__ __launch_bounds__(THREADS, 4) void gemm_trace(
    const float* __restrict__ x, const ushort* __restrict__ obf,
    float* __restrict__ part)
{
    __shared__ __align__(16) char Ab[2][16384];
    __shared__ __align__(16) char Bb[2][16384];

    const int tid  = threadIdx.x;
    const int lane = tid & 63;
    const int wid  = tid >> 6;      // 0..7
    const int wm   = wid >> 2;      // 0..1 (row half)
    const int wn   = wid & 3;       // 0..3 (time quarter)
    const int rb   = blockIdx.x;    // 0..15 (row block of 128)
    const int d    = blockIdx.y;    // 0..31 (batch)
    const int t0   = (d * 16 + rb) & 63;   // K starting phase

    const char* ab = (const char*)(x + (size_t)d * DDIM * DDIM + (size_t)rb * 128 * DDIM);
    const char* bb = (const char*)obf;

    // staging: A 1024 chunks (128 rows x 8), B 1024 chunks (256 rows x 4); 2 each/thread
    const int ar0 = tid >> 3,         aq0 = ((tid & 7) ^ (ar0 & 7)) * 16;
    const int ar1 = (tid + 512) >> 3, aq1 = (((tid + 512) & 7) ^ (ar1 & 7)) * 16;
    const int br0 = tid >> 2,         bq0 = ((tid & 3) ^ (br0 & 3)) * 16;
    const int br1 = (tid + 512) >> 2, bq1 = (((tid + 512) & 3) ^ (br1 & 3)) * 16;

    const char* as0 = ab + (size_t)ar0 * (DDIM * 4) + aq0;
    const char* as1 = ab + (size_t)ar1 * (DDIM * 4) + aq1;
    const char* bs0 = bb + (size_t)br0 * (DDIM * 2) + bq0;
    const char* bs1 = bb + (size_t)br1 * (DDIM * 2) + bq1;

#define STAGE(t, buf) do {                                \
    gld16(as0 + (t) * 128, &Ab[buf][tid * 16]);           \
    gld16(as1 + (t) * 128, &Ab[buf][(tid + 512) * 16]);   \
    gld16(bs0 + (t) * 64,  &Bb[buf][tid * 16]);           \
    gld16(bs1 + (t) * 64,  &Bb[buf][(tid + 512) * 16]);   \
} while (0)

    const int lr = lane & 15;       // row-in-16 (A) / time-in-16 (B)
    const int lq = lane >> 4;       // k-quarter

    int aoff0[4], aoff1[4], boff[4];
    #pragma unroll
    for (int mi = 0; mi < 4; ++mi) {
        const int r = wm * 64 + mi * 16 + lr;
        aoff0[mi] = r * 128 + ((2 * lq)     ^ (r & 7)) * 16;
        aoff1[mi] = r * 128 + ((2 * lq + 1) ^ (r & 7)) * 16;
    }
    #pragma unroll
    for (int ni = 0; ni < 4; ++ni) {
        const int rt = wn * 64 + ni * 16 + lr;
        boff[ni] = rt * 64 + (lq ^ (rt & 3)) * 16;
    }

    f32x4 acc[4][4];
    #pragma unroll
    for (int mi = 0; mi < 4; ++mi)
        #pragma unroll
        for (int ni = 0; ni < 4; ++ni)
            acc[mi][ni] = (f32x4){0.f, 0.f, 0.f, 0.f};

    STAGE(t0, 0);
    #pragma unroll 1
    for (int i = 0; i < NT; ++i) {
        const int cur = i & 1;
        if (i + 1 < NT) {
            STAGE(((t0 + i + 1) & 63), cur ^ 1);           // in flight across barrier
            asm volatile("s_waitcnt vmcnt(4)" ::: "memory");   // tile i's 4 loads done
        } else {
            asm volatile("s_waitcnt vmcnt(0)" ::: "memory");
        }
        __builtin_amdgcn_sched_barrier(0);
        __builtin_amdgcn_s_barrier();                      // all waves' tile-i DMA visible
        __builtin_amdgcn_sched_barrier(0);

        short8 af[4], bfr[4];
        #pragma unroll
        for (int mi = 0; mi < 4; ++mi) {
            const float4 lo = *(const float4*)&Ab[cur][aoff0[mi]];
            const float4 hi = *(const float4*)&Ab[cur][aoff1[mi]];
            short8 a8;
            a8[0] = cvt1(lo.x); a8[1] = cvt1(lo.y); a8[2] = cvt1(lo.z); a8[3] = cvt1(lo.w);
            a8[4] = cvt1(hi.x); a8[5] = cvt1(hi.y); a8[6] = cvt1(hi.z); a8[7] = cvt1(hi.w);
            af[mi] = a8;
        }
        #pragma unroll
        for (int ni = 0; ni < 4; ++ni)
            bfr[ni] = *(const short8*)&Bb[cur][boff[ni]];
        #pragma unroll
        for (int mi = 0; mi < 4; ++mi)
            #pragma unroll
            for (int ni = 0; ni < 4; ++ni)
                acc[mi][ni] = __builtin_amdgcn_mfma_f32_16x16x32_bf16(
                    af[mi], bfr[ni], acc[mi][ni], 0, 0, 0);

        __builtin_amdgcn_sched_barrier(0);
        __builtin_amdgcn_s_barrier();                      // buf[cur] free for overwrite
        __builtin_amdgcn_sched_barrier(0);
    }
#undef STAGE

    // ---- fused trace epilogue: weight acc rows by o[a][row], reduce ----
    // acc[mi][ni][j]: row = rb*128 + wm*64 + mi*16 + lq*4 + j, time = wn*64 + ni*16 + lr
    float* plds = (float*)&Ab[0][0];   // 2 x 256 floats (LDS free after last barrier)

    #pragma unroll
    for (int ni = 0; ni < 4; ++ni) {
        const int a_idx = wn * 64 + ni * 16 + lr;
        float ps = 0.f;
        #pragma unroll
        for (int mi = 0; mi < 4; ++mi) {
            const int bg = rb * 128 + wm * 64 + mi * 16 + lq * 4;
            const ushort4 w = *(const ushort4*)(obf + (size_t)a_idx * DDIM + bg);
            ps += bf2f(w.x) * acc[mi][ni][0];
            ps += bf2f(w.y) * acc[mi][ni][1];
            ps += bf2f(w.z) * acc[mi][ni][2];
            ps += bf2f(w.w) * acc[mi][ni][3];
        }
        ps += __shfl_xor(ps, 16);
        ps += __shfl_xor(ps, 32);
        if (lane < 16) plds[wm * 256 + a_idx] = ps;
    }
    __syncthreads();
    if (tid < 256)
        part[((size_t)d * 16 + rb) * TTIMES + tid] = plds[tid] + plds[256 + tid];
}

// ---------------- final reduce over row-blocks ----------------
__global__ void reduce_part(const float* __restrict__ part, float* __restrict__ out) {
    const int d = blockIdx.x;    // 32
    const int a = threadIdx.x;   // 256
    float s = 0.f;
    #pragma unroll
    for (int rb = 0; rb < 16; ++rb)
        s += part[((size_t)d * 16 + rb) * TTIMES + a];
    out[(size_t)d * TTIMES + a] = s;
}

extern "C" void kernel_launch(void* const* d_in, const int* in_sizes, int n_in,
                              void* d_out, int out_size, void* d_ws, size_t ws_size,
                              hipStream_t stream) {
    const float* x   = (const float*)d_in[0];   // (32, 2048, 2048) fp32
    const float* org = (const float*)d_in[1];   // (256, 2048) fp32
    float* out = (float*)d_out;                 // (32, 256) fp32

    ushort* obf = (ushort*)d_ws;                          // 1 MiB bf16 normalized o
    float*  prt = (float*)((char*)d_ws + (1 << 20));      // 512 KiB partials (32x16x256)

    norm_rows<<<dim3(TTIMES), dim3(256), 0, stream>>>(org, obf);
    gemm_trace<<<dim3(16, 32), dim3(THREADS), 0, stream>>>(x, obf, prt);
    reduce_part<<<dim3(32), dim3(256), 0, stream>>>(prt, out);
}